// Round 3
// baseline (356.427 us; speedup 1.0000x reference)
//
#include <hip/hip_runtime.h>
#include <stdint.h>

#define NN 8192
#define IN_DIM 32
#define HID_DIM 64
#define OUT_DIM 16

typedef __attribute__((ext_vector_type(8))) short short8;
typedef __attribute__((ext_vector_type(4))) float f32x4;

// fp32 -> bf16 bits, round-to-nearest-even
__device__ __forceinline__ short f2bf_bits(float x){
  uint32_t u = __builtin_bit_cast(uint32_t, x);
  u += 0x7FFFu + ((u >> 16) & 1u);
  return (short)(u >> 16);
}

__device__ __forceinline__ short8 cvt8(f32x4 lo, f32x4 hi){
  short8 r;
  r[0]=f2bf_bits(lo[0]); r[1]=f2bf_bits(lo[1]); r[2]=f2bf_bits(lo[2]); r[3]=f2bf_bits(lo[3]);
  r[4]=f2bf_bits(hi[0]); r[5]=f2bf_bits(hi[1]); r[6]=f2bf_bits(hi[2]); r[7]=f2bf_bits(hi[3]);
  return r;
}

// Kernel 0: Gt[c][r] = bf16( (X @ W1)[r][c] )   [64][8192]
// 2048 blocks: 128 row-groups x 16 col-groups; wave = fixed c, 64 consecutive r.
__global__ __launch_bounds__(256) void k_g(const float* __restrict__ X, const float* __restrict__ W1,
                                           short* __restrict__ Gt){
  const int b    = blockIdx.x;
  const int rb   = (b & 127) * 64;
  const int cg   = b >> 7;                       // 0..15
  const int lane = threadIdx.x & 63;
  const int c    = cg * 4 + (threadIdx.x >> 6);  // uniform per wave
  const int r    = rb + lane;
  const float* xr = X + (size_t)r * IN_DIM;
  float acc = 0.f;
  #pragma unroll
  for (int k = 0; k < IN_DIM; ++k)
    acc += xr[k] * W1[(size_t)k * HID_DIM + c];
  Gt[(size_t)c * NN + r] = f2bf_bits(acc);       // contiguous 128B per wave
}

// mm forward: P{1,2}[ks][row][0..63] = adj{1,2}[rows][krange] @ Bt^T
// Bt is [64][8192] bf16. wave = 16 rows; block = 4 waves; grid (128, S).
__global__ __launch_bounds__(256, 4) void mm_fwd(const float* __restrict__ adj1, const float* __restrict__ adj2,
                                                 const short* __restrict__ Bt,
                                                 float* __restrict__ P1, float* __restrict__ P2, int klen){
  const int lane = threadIdx.x & 63;
  const int wave = threadIdx.x >> 6;
  const int bm   = blockIdx.x;
  const int ks   = blockIdx.y;
  const int arow = bm * 64 + wave * 16 + (lane & 15);
  const int kgrp = (lane >> 4) * 8;
  const int k0   = ks * klen;

  const float* a1 = adj1 + (size_t)arow * NN + k0 + kgrp;
  const float* a2 = adj2 + (size_t)arow * NN + k0 + kgrp;
  const short* bp[4];
  #pragma unroll
  for (int f = 0; f < 4; ++f)
    bp[f] = Bt + (size_t)(f * 16 + (lane & 15)) * NN + k0 + kgrp;

  f32x4 acc1[4] = {{0.f,0.f,0.f,0.f},{0.f,0.f,0.f,0.f},{0.f,0.f,0.f,0.f},{0.f,0.f,0.f,0.f}};
  f32x4 acc2[4] = {{0.f,0.f,0.f,0.f},{0.f,0.f,0.f,0.f},{0.f,0.f,0.f,0.f},{0.f,0.f,0.f,0.f}};

  const int nsteps = klen >> 5;
  f32x4 A1l = *(const f32x4*)(a1), A1h = *(const f32x4*)(a1 + 4);
  f32x4 A2l = *(const f32x4*)(a2), A2h = *(const f32x4*)(a2 + 4);
  short8 B[4];
  #pragma unroll
  for (int f = 0; f < 4; ++f) B[f] = *(const short8*)(bp[f]);

  #pragma unroll 1
  for (int t = 0; t < nsteps - 1; ++t){
    a1 += 32; a2 += 32;
    #pragma unroll
    for (int f = 0; f < 4; ++f) bp[f] += 32;
    f32x4 nA1l = *(const f32x4*)(a1), nA1h = *(const f32x4*)(a1 + 4);
    f32x4 nA2l = *(const f32x4*)(a2), nA2h = *(const f32x4*)(a2 + 4);
    short8 nB[4];
    #pragma unroll
    for (int f = 0; f < 4; ++f) nB[f] = *(const short8*)(bp[f]);
    short8 fa1 = cvt8(A1l, A1h);
    short8 fa2 = cvt8(A2l, A2h);
    #pragma unroll
    for (int f = 0; f < 4; ++f){
      acc1[f] = __builtin_amdgcn_mfma_f32_16x16x32_bf16(fa1, B[f], acc1[f], 0, 0, 0);
      acc2[f] = __builtin_amdgcn_mfma_f32_16x16x32_bf16(fa2, B[f], acc2[f], 0, 0, 0);
    }
    A1l = nA1l; A1h = nA1h; A2l = nA2l; A2h = nA2h;
    #pragma unroll
    for (int f = 0; f < 4; ++f) B[f] = nB[f];
  }
  {
    short8 fa1 = cvt8(A1l, A1h);
    short8 fa2 = cvt8(A2l, A2h);
    #pragma unroll
    for (int f = 0; f < 4; ++f){
      acc1[f] = __builtin_amdgcn_mfma_f32_16x16x32_bf16(fa1, B[f], acc1[f], 0, 0, 0);
      acc2[f] = __builtin_amdgcn_mfma_f32_16x16x32_bf16(fa2, B[f], acc2[f], 0, 0, 0);
    }
  }

  const int orow = bm * 64 + wave * 16 + (lane >> 4) * 4;
  const int col  = lane & 15;
  float* p1 = P1 + ((size_t)ks * NN + orow) * HID_DIM + col;
  float* p2 = P2 + ((size_t)ks * NN + orow) * HID_DIM + col;
  #pragma unroll
  for (int r = 0; r < 4; ++r){
    #pragma unroll
    for (int f = 0; f < 4; ++f){
      p1[(size_t)r * HID_DIM + f * 16] = acc1[f][r];
      p2[(size_t)r * HID_DIM + f * 16] = acc2[f][r];
    }
  }
}

// mm reverse: identical math, reversed block ids + descending K (L3 ping-pong).
__global__ __launch_bounds__(256, 4) void mm_rev(const float* __restrict__ adj1, const float* __restrict__ adj2,
                                                 const short* __restrict__ Bt,
                                                 float* __restrict__ P1, float* __restrict__ P2, int klen){
  const int lane = threadIdx.x & 63;
  const int wave = threadIdx.x >> 6;
  const int bm   = gridDim.x - 1 - blockIdx.x;
  const int ks   = gridDim.y - 1 - blockIdx.y;
  const int arow = bm * 64 + wave * 16 + (lane & 15);
  const int kgrp = (lane >> 4) * 8;
  const int nsteps = klen >> 5;
  const int klast  = ks * klen + (nsteps - 1) * 32;

  const float* a1 = adj1 + (size_t)arow * NN + klast + kgrp;
  const float* a2 = adj2 + (size_t)arow * NN + klast + kgrp;
  const short* bp[4];
  #pragma unroll
  for (int f = 0; f < 4; ++f)
    bp[f] = Bt + (size_t)(f * 16 + (lane & 15)) * NN + klast + kgrp;

  f32x4 acc1[4] = {{0.f,0.f,0.f,0.f},{0.f,0.f,0.f,0.f},{0.f,0.f,0.f,0.f},{0.f,0.f,0.f,0.f}};
  f32x4 acc2[4] = {{0.f,0.f,0.f,0.f},{0.f,0.f,0.f,0.f},{0.f,0.f,0.f,0.f},{0.f,0.f,0.f,0.f}};

  f32x4 A1l = *(const f32x4*)(a1), A1h = *(const f32x4*)(a1 + 4);
  f32x4 A2l = *(const f32x4*)(a2), A2h = *(const f32x4*)(a2 + 4);
  short8 B[4];
  #pragma unroll
  for (int f = 0; f < 4; ++f) B[f] = *(const short8*)(bp[f]);

  #pragma unroll 1
  for (int t = 0; t < nsteps - 1; ++t){
    a1 -= 32; a2 -= 32;
    #pragma unroll
    for (int f = 0; f < 4; ++f) bp[f] -= 32;
    f32x4 nA1l = *(const f32x4*)(a1), nA1h = *(const f32x4*)(a1 + 4);
    f32x4 nA2l = *(const f32x4*)(a2), nA2h = *(const f32x4*)(a2 + 4);
    short8 nB[4];
    #pragma unroll
    for (int f = 0; f < 4; ++f) nB[f] = *(const short8*)(bp[f]);
    short8 fa1 = cvt8(A1l, A1h);
    short8 fa2 = cvt8(A2l, A2h);
    #pragma unroll
    for (int f = 0; f < 4; ++f){
      acc1[f] = __builtin_amdgcn_mfma_f32_16x16x32_bf16(fa1, B[f], acc1[f], 0, 0, 0);
      acc2[f] = __builtin_amdgcn_mfma_f32_16x16x32_bf16(fa2, B[f], acc2[f], 0, 0, 0);
    }
    A1l = nA1l; A1h = nA1h; A2l = nA2l; A2h = nA2h;
    #pragma unroll
    for (int f = 0; f < 4; ++f) B[f] = nB[f];
  }
  {
    short8 fa1 = cvt8(A1l, A1h);
    short8 fa2 = cvt8(A2l, A2h);
    #pragma unroll
    for (int f = 0; f < 4; ++f){
      acc1[f] = __builtin_amdgcn_mfma_f32_16x16x32_bf16(fa1, B[f], acc1[f], 0, 0, 0);
      acc2[f] = __builtin_amdgcn_mfma_f32_16x16x32_bf16(fa2, B[f], acc2[f], 0, 0, 0);
    }
  }

  const int orow = bm * 64 + wave * 16 + (lane >> 4) * 4;
  const int col  = lane & 15;
  float* p1 = P1 + ((size_t)ks * NN + orow) * HID_DIM + col;
  float* p2 = P2 + ((size_t)ks * NN + orow) * HID_DIM + col;
  #pragma unroll
  for (int r = 0; r < 4; ++r){
    #pragma unroll
    for (int f = 0; f < 4; ++f){
      p1[(size_t)r * HID_DIM + f * 16] = acc1[f][r];
      p2[(size_t)r * HID_DIM + f * 16] = acc2[f][r];
    }
  }
}

// l1_combine: H1t[c][r] = bf16( relu(SY1+b1) + relu(SY2+b1) ). wave=1 row, c=lane.
__global__ __launch_bounds__(256) void l1_combine(const float* __restrict__ Y1p, const float* __restrict__ Y2p,
                                                  const float* __restrict__ b1,
                                                  short* __restrict__ H1t, int S){
  const int lane = threadIdx.x & 63;
  const int wave = threadIdx.x >> 6;
  const int row  = blockIdx.x * 4 + wave;
  float s1 = 0.f, s2 = 0.f;
  for (int sp = 0; sp < S; ++sp){
    s1 += Y1p[((size_t)sp * NN + row) * HID_DIM + lane];
    s2 += Y2p[((size_t)sp * NN + row) * HID_DIM + lane];
  }
  const float b = b1[lane];
  float h = fmaxf(s1 + b, 0.f) + fmaxf(s2 + b, 0.f);
  H1t[(size_t)lane * NN + row] = f2bf_bits(h);
}

// l2_combine: out[row][c] = relu(Z1@W2+b2) + relu(Z2@W2+b2), 4 rows/block
__global__ __launch_bounds__(256) void l2_combine(const float* __restrict__ Z1p, const float* __restrict__ Z2p,
                                                  const float* __restrict__ W2, const float* __restrict__ b2,
                                                  float* __restrict__ out, int S){
  __shared__ float sW[HID_DIM * OUT_DIM];
  __shared__ float sb[OUT_DIM];
  __shared__ float sz[4][2][HID_DIM];
  const int tid = threadIdx.x;
  for (int i = tid; i < HID_DIM * OUT_DIM; i += 256) sW[i] = W2[i];
  if (tid < OUT_DIM) sb[tid] = b2[tid];
  const int sub = tid >> 6, t = tid & 63;
  const int row = blockIdx.x * 4 + sub;
  float s1 = 0.f, s2 = 0.f;
  for (int sp = 0; sp < S; ++sp){
    s1 += Z1p[((size_t)sp * NN + row) * HID_DIM + t];
    s2 += Z2p[((size_t)sp * NN + row) * HID_DIM + t];
  }
  sz[sub][0][t] = s1;
  sz[sub][1][t] = s2;
  __syncthreads();
  if (t < OUT_DIM){
    float a = sb[t], b = sb[t];
    #pragma unroll
    for (int k = 0; k < HID_DIM; ++k){
      a += sz[sub][0][k] * sW[k * OUT_DIM + t];
      b += sz[sub][1][k] * sW[k * OUT_DIM + t];
    }
    out[(size_t)row * OUT_DIM + t] = fmaxf(a, 0.f) + fmaxf(b, 0.f);
  }
}

extern "C" void kernel_launch(void* const* d_in, const int* in_sizes, int n_in,
                              void* d_out, int out_size, void* d_ws, size_t ws_size,
                              hipStream_t stream){
  const float* adj1 = (const float*)d_in[0];
  const float* adj2 = (const float*)d_in[1];
  const float* X    = (const float*)d_in[2];
  const float* W1   = (const float*)d_in[3];
  const float* b1   = (const float*)d_in[4];
  const float* W2   = (const float*)d_in[5];
  const float* b2   = (const float*)d_in[6];
  float* out = (float*)d_out;

  char* ws = (char*)d_ws;
  short* Gt  = (short*)ws;                           // 64*8192*2 = 1 MB
  short* H1t = (short*)(ws + (size_t)1024 * 1024);   // 1 MB
  const size_t off = (size_t)2 * 1024 * 1024;

  // Per split: 2 MB per branch-buffer (8192*64*4). Y (layer1) and Z (layer2)
  // alias: sequential lifetimes. S=8 -> 32 MB partials + 2 MB operands.
  int S = 8;
  while (S > 1 && off + (size_t)S * 4 * 1024 * 1024 > ws_size) S >>= 1;
  float* P1 = (float*)(ws + off);
  float* P2 = P1 + (size_t)S * NN * HID_DIM;
  const int klen = NN / S;

  k_g      <<<dim3(2048),       dim3(256), 0, stream>>>(X, W1, Gt);
  mm_fwd   <<<dim3(NN / 64, S), dim3(256), 0, stream>>>(adj1, adj2, Gt, P1, P2, klen);
  l1_combine<<<dim3(NN / 4),    dim3(256), 0, stream>>>(P1, P2, b1, H1t, S);
  mm_rev   <<<dim3(NN / 64, S), dim3(256), 0, stream>>>(adj1, adj2, H1t, P1, P2, klen);
  l2_combine<<<dim3(NN / 4),    dim3(256), 0, stream>>>(P1, P2, W2, b2, out, S);
}

// Round 4
// 266.652 us; speedup vs baseline: 1.3367x; 1.3367x over previous
//
#include <hip/hip_runtime.h>
#include <stdint.h>

#define NN 8192
#define IN_DIM 32
#define HID_DIM 64
#define OUT_DIM 16

typedef __attribute__((ext_vector_type(8))) short short8;
typedef __attribute__((ext_vector_type(4))) float f32x4;

// fp32 -> bf16 bits, round-to-nearest-even
__device__ __forceinline__ short f2bf_bits(float x){
  uint32_t u = __builtin_bit_cast(uint32_t, x);
  u += 0x7FFFu + ((u >> 16) & 1u);
  return (short)(u >> 16);
}

__device__ __forceinline__ short8 cvt8(f32x4 lo, f32x4 hi){
  short8 r;
  r[0]=f2bf_bits(lo[0]); r[1]=f2bf_bits(lo[1]); r[2]=f2bf_bits(lo[2]); r[3]=f2bf_bits(lo[3]);
  r[4]=f2bf_bits(hi[0]); r[5]=f2bf_bits(hi[1]); r[6]=f2bf_bits(hi[2]); r[7]=f2bf_bits(hi[3]);
  return r;
}

// Kernel 0: Gt[c][r] = bf16( (X @ W1)[r][c] )   [64][8192]
__global__ __launch_bounds__(256) void k_g(const float* __restrict__ X, const float* __restrict__ W1,
                                           short* __restrict__ Gt){
  const int b    = blockIdx.x;
  const int rb   = (b & 127) * 64;
  const int cg   = b >> 7;
  const int lane = threadIdx.x & 63;
  const int c    = cg * 4 + (threadIdx.x >> 6);
  const int r    = rb + lane;
  const float* xr = X + (size_t)r * IN_DIM;
  float acc = 0.f;
  #pragma unroll
  for (int k = 0; k < IN_DIM; ++k)
    acc += xr[k] * W1[(size_t)k * HID_DIM + c];
  Gt[(size_t)c * NN + r] = f2bf_bits(acc);
}

// mm: P{1,2}[ks][row][0..63] = adj{1,2}[rows][krange] @ Bt^T, Bt [64][8192] bf16.
// LDS-staged: per K-group stage adj1/adj2 tiles [64 rows][128 cols f32] (32 KB each)
// via global_load_lds with 512 B contiguous per row (DRAM-page friendly), granule
// XOR-swizzled at the GLOBAL source (LDS dest linear, per m104/m173).
// Block = 256 threads (4 waves, 16 rows each). 64 KB LDS -> 2 blocks/CU.
template<int REV>
__global__ __launch_bounds__(256) void mm_lds(const float* __restrict__ adj1, const float* __restrict__ adj2,
                                              const short* __restrict__ Bt,
                                              float* __restrict__ P1, float* __restrict__ P2, int klen){
  __shared__ __align__(16) float sA1[64 * 128];
  __shared__ __align__(16) float sA2[64 * 128];
  const int tid  = threadIdx.x;
  const int lane = tid & 63;
  const int wave = tid >> 6;
  const int bm   = REV ? ((int)gridDim.x - 1 - (int)blockIdx.x) : (int)blockIdx.x;
  const int ks   = REV ? ((int)gridDim.y - 1 - (int)blockIdx.y) : (int)blockIdx.y;
  const int k0   = ks * klen;
  const int ngrp = klen >> 7;          // K-groups of 128 cols

  // staging constants (per thread): load p covers tile row p*8 + (tid>>5),
  // granule (16B) index tid&31, swizzled source granule = (tid&31) ^ (row&7)
  const int srow = tid >> 5;                       // 0..7
  const int sgg  = (tid & 31) ^ (srow & 7);        // source granule
  const size_t grow_base = (size_t)(bm * 64) * NN; // block's first row

  // compute constants
  const int rl = wave * 16 + (lane & 15);          // tile row this lane reads
  const int sw = lane & 7;                         // row swizzle key (rl&7 == lane&7)
  const int qh = lane >> 4;                        // k-group-of-8 within frag

  f32x4 acc1[4] = {{0,0,0,0},{0,0,0,0},{0,0,0,0},{0,0,0,0}};
  f32x4 acc2[4] = {{0,0,0,0},{0,0,0,0},{0,0,0,0},{0,0,0,0}};

  #pragma unroll 1
  for (int gi = 0; gi < ngrp; ++gi){
    const int g     = REV ? (ngrp - 1 - gi) : gi;
    const int kbase = k0 + g * 128;

    if (gi) __syncthreads();           // previous compute done before overwrite

    // ---- stage: 8 rounds x 2 matrices, 16B per thread per round ----
    {
      const size_t colb = (size_t)kbase + (size_t)sgg * 4;
      #pragma unroll
      for (int p = 0; p < 8; ++p){
        const float* s1 = adj1 + grow_base + (size_t)(p * 8 + srow) * NN + colb;
        const float* s2 = adj2 + grow_base + (size_t)(p * 8 + srow) * NN + colb;
        __builtin_amdgcn_global_load_lds(
            (const __attribute__((address_space(1))) void*)s1,
            (__attribute__((address_space(3))) void*)&sA1[p * 1024 + tid * 4], 16, 0, 0);
        __builtin_amdgcn_global_load_lds(
            (const __attribute__((address_space(1))) void*)s2,
            (__attribute__((address_space(3))) void*)&sA2[p * 1024 + tid * 4], 16, 0, 0);
      }
    }
    __syncthreads();                   // compiler drains vmcnt before barrier

    // ---- compute: 4 k-steps of 32 ----
    #pragma unroll
    for (int j = 0; j < 4; ++j){
      const int gr0 = j * 8 + qh * 2;            // first granule of A-frag
      const int o0  = rl * 128 + ((gr0     ^ sw) << 2);
      const int o1  = rl * 128 + (((gr0+1) ^ sw) << 2);
      f32x4 lo1 = *(const f32x4*)&sA1[o0];
      f32x4 hi1 = *(const f32x4*)&sA1[o1];
      f32x4 lo2 = *(const f32x4*)&sA2[o0];
      f32x4 hi2 = *(const f32x4*)&sA2[o1];
      short8 b[4];
      const size_t bk = (size_t)kbase + j * 32 + qh * 8;
      #pragma unroll
      for (int f = 0; f < 4; ++f)
        b[f] = *(const short8*)(Bt + (size_t)(f * 16 + (lane & 15)) * NN + bk);
      short8 fa1 = cvt8(lo1, hi1);
      short8 fa2 = cvt8(lo2, hi2);
      #pragma unroll
      for (int f = 0; f < 4; ++f){
        acc1[f] = __builtin_amdgcn_mfma_f32_16x16x32_bf16(fa1, b[f], acc1[f], 0, 0, 0);
        acc2[f] = __builtin_amdgcn_mfma_f32_16x16x32_bf16(fa2, b[f], acc2[f], 0, 0, 0);
      }
    }
  }

  // D layout: col = lane&15, row = (lane>>4)*4 + reg
  const int orow = bm * 64 + wave * 16 + qh * 4;
  const int col  = lane & 15;
  float* p1 = P1 + ((size_t)ks * NN + orow) * HID_DIM + col;
  float* p2 = P2 + ((size_t)ks * NN + orow) * HID_DIM + col;
  #pragma unroll
  for (int r = 0; r < 4; ++r){
    #pragma unroll
    for (int f = 0; f < 4; ++f){
      p1[(size_t)r * HID_DIM + f * 16] = acc1[f][r];
      p2[(size_t)r * HID_DIM + f * 16] = acc2[f][r];
    }
  }
}

// l1_combine: H1t[c][r] = bf16( relu(SY1+b1) + relu(SY2+b1) )
__global__ __launch_bounds__(256) void l1_combine(const float* __restrict__ Y1p, const float* __restrict__ Y2p,
                                                  const float* __restrict__ b1,
                                                  short* __restrict__ H1t, int S){
  const int lane = threadIdx.x & 63;
  const int wave = threadIdx.x >> 6;
  const int row  = blockIdx.x * 4 + wave;
  float s1 = 0.f, s2 = 0.f;
  for (int sp = 0; sp < S; ++sp){
    s1 += Y1p[((size_t)sp * NN + row) * HID_DIM + lane];
    s2 += Y2p[((size_t)sp * NN + row) * HID_DIM + lane];
  }
  const float b = b1[lane];
  float h = fmaxf(s1 + b, 0.f) + fmaxf(s2 + b, 0.f);
  H1t[(size_t)lane * NN + row] = f2bf_bits(h);
}

// l2_combine: out[row][c] = relu(Z1@W2+b2) + relu(Z2@W2+b2)
__global__ __launch_bounds__(256) void l2_combine(const float* __restrict__ Z1p, const float* __restrict__ Z2p,
                                                  const float* __restrict__ W2, const float* __restrict__ b2,
                                                  float* __restrict__ out, int S){
  __shared__ float sW[HID_DIM * OUT_DIM];
  __shared__ float sb[OUT_DIM];
  __shared__ float sz[4][2][HID_DIM];
  const int tid = threadIdx.x;
  for (int i = tid; i < HID_DIM * OUT_DIM; i += 256) sW[i] = W2[i];
  if (tid < OUT_DIM) sb[tid] = b2[tid];
  const int sub = tid >> 6, t = tid & 63;
  const int row = blockIdx.x * 4 + sub;
  float s1 = 0.f, s2 = 0.f;
  for (int sp = 0; sp < S; ++sp){
    s1 += Z1p[((size_t)sp * NN + row) * HID_DIM + t];
    s2 += Z2p[((size_t)sp * NN + row) * HID_DIM + t];
  }
  sz[sub][0][t] = s1;
  sz[sub][1][t] = s2;
  __syncthreads();
  if (t < OUT_DIM){
    float a = sb[t], b = sb[t];
    #pragma unroll
    for (int k = 0; k < HID_DIM; ++k){
      a += sz[sub][0][k] * sW[k * OUT_DIM + t];
      b += sz[sub][1][k] * sW[k * OUT_DIM + t];
    }
    out[(size_t)row * OUT_DIM + t] = fmaxf(a, 0.f) + fmaxf(b, 0.f);
  }
}

extern "C" void kernel_launch(void* const* d_in, const int* in_sizes, int n_in,
                              void* d_out, int out_size, void* d_ws, size_t ws_size,
                              hipStream_t stream){
  const float* adj1 = (const float*)d_in[0];
  const float* adj2 = (const float*)d_in[1];
  const float* X    = (const float*)d_in[2];
  const float* W1   = (const float*)d_in[3];
  const float* b1   = (const float*)d_in[4];
  const float* W2   = (const float*)d_in[5];
  const float* b2   = (const float*)d_in[6];
  float* out = (float*)d_out;

  char* ws = (char*)d_ws;
  short* Gt  = (short*)ws;                           // 64*8192*2 = 1 MB
  short* H1t = (short*)(ws + (size_t)1024 * 1024);   // 1 MB
  const size_t off = (size_t)2 * 1024 * 1024;

  // S=4: 512 blocks = exactly 2 resident blocks/CU (LDS-limited), and only
  // 16 MB of partials (P1+P2, reused across layers).
  int S = 4;
  while (S > 1 && off + (size_t)S * 4 * 1024 * 1024 > ws_size) S >>= 1;
  float* P1 = (float*)(ws + off);
  float* P2 = P1 + (size_t)S * NN * HID_DIM;
  const int klen = NN / S;

  k_g        <<<dim3(2048),       dim3(256), 0, stream>>>(X, W1, Gt);
  mm_lds<0>  <<<dim3(NN / 64, S), dim3(256), 0, stream>>>(adj1, adj2, Gt, P1, P2, klen);
  l1_combine <<<dim3(NN / 4),     dim3(256), 0, stream>>>(P1, P2, b1, H1t, S);
  mm_lds<1>  <<<dim3(NN / 64, S), dim3(256), 0, stream>>>(adj1, adj2, H1t, P1, P2, klen);
  l2_combine <<<dim3(NN / 4),     dim3(256), 0, stream>>>(P1, P2, W2, b2, out, S);
}

// Round 5
// 260.751 us; speedup vs baseline: 1.3669x; 1.0226x over previous
//
#include <hip/hip_runtime.h>
#include <stdint.h>

#define NN 8192
#define IN_DIM 32
#define HID_DIM 64
#define OUT_DIM 16

typedef __attribute__((ext_vector_type(8))) short short8;
typedef __attribute__((ext_vector_type(4))) float f32x4;

// fp32 -> bf16 bits, round-to-nearest-even
__device__ __forceinline__ short f2bf_bits(float x){
  uint32_t u = __builtin_bit_cast(uint32_t, x);
  u += 0x7FFFu + ((u >> 16) & 1u);
  return (short)(u >> 16);
}

__device__ __forceinline__ short8 cvt8(f32x4 lo, f32x4 hi){
  short8 r;
  r[0]=f2bf_bits(lo[0]); r[1]=f2bf_bits(lo[1]); r[2]=f2bf_bits(lo[2]); r[3]=f2bf_bits(lo[3]);
  r[4]=f2bf_bits(hi[0]); r[5]=f2bf_bits(hi[1]); r[6]=f2bf_bits(hi[2]); r[7]=f2bf_bits(hi[3]);
  return r;
}

// Kernel 0: Gt[c][r] = bf16( (X @ W1)[r][c] )   [64][8192]
__global__ __launch_bounds__(256) void k_g(const float* __restrict__ X, const float* __restrict__ W1,
                                           short* __restrict__ Gt){
  const int b    = blockIdx.x;
  const int rb   = (b & 127) * 64;
  const int cg   = b >> 7;
  const int lane = threadIdx.x & 63;
  const int c    = cg * 4 + (threadIdx.x >> 6);
  const int r    = rb + lane;
  const float* xr = X + (size_t)r * IN_DIM;
  float acc = 0.f;
  #pragma unroll
  for (int k = 0; k < IN_DIM; ++k)
    acc += xr[k] * W1[(size_t)k * HID_DIM + c];
  Gt[(size_t)c * NN + r] = f2bf_bits(acc);
}

// mm, double-buffered: P{1,2} = adj{1,2}[rows][kr] @ Bt^T  (Bt [64][8192] bf16)
// K-group = 64 cols. LDS sA[2 buf][2 mat][64x64 f32] = 64 KB -> 2 blocks/CU.
// Loop: stage(next group -> other buf) BEFORE compute(current buf); one barrier
// per group (compiler drains vmcnt there) => staging in flight under compute.
template<int REV>
__global__ __launch_bounds__(256) void mm_db(const float* __restrict__ adj1, const float* __restrict__ adj2,
                                             const short* __restrict__ Bt,
                                             float* __restrict__ P1, float* __restrict__ P2, int klen){
  __shared__ __align__(16) float sA[2][2][64 * 64];
  const int tid  = threadIdx.x;
  const int lane = tid & 63;
  const int wave = tid >> 6;
  const int bm   = REV ? ((int)gridDim.x - 1 - (int)blockIdx.x) : (int)blockIdx.x;
  const int ks   = REV ? ((int)gridDim.y - 1 - (int)blockIdx.y) : (int)blockIdx.y;
  const int k0   = ks * klen;
  const int ngrp = klen >> 6;

  // staging: round p covers rows p*16+(tid>>4); granule (16B) = tid&15,
  // XOR-swizzled at the GLOBAL source (LDS dest stays wave-linear).
  const int srow = tid >> 4;                        // 0..15
  const int sg   = (tid & 15) ^ (srow & 7);         // swizzled source granule
  const size_t growb = (size_t)(bm * 64) * NN;

  // compute: lane reads tile row rl, A-frag = 8 floats = granules gr0,gr0+1
  const int rl = wave * 16 + (lane & 15);
  const int sw = lane & 7;                          // rl&7 == lane&7
  const int qh = lane >> 4;

  f32x4 acc1[4] = {{0,0,0,0},{0,0,0,0},{0,0,0,0},{0,0,0,0}};
  f32x4 acc2[4] = {{0,0,0,0},{0,0,0,0},{0,0,0,0},{0,0,0,0}};

  auto stage = [&](int t){
    const int g     = REV ? (ngrp - 1 - t) : t;
    const int buf   = t & 1;
    const size_t colb = (size_t)(k0 + g * 64) + (size_t)sg * 4;
    #pragma unroll
    for (int p = 0; p < 4; ++p){
      const float* s1 = adj1 + growb + (size_t)(p * 16 + srow) * NN + colb;
      const float* s2 = adj2 + growb + (size_t)(p * 16 + srow) * NN + colb;
      __builtin_amdgcn_global_load_lds(
          (const __attribute__((address_space(1))) void*)s1,
          (__attribute__((address_space(3))) void*)&sA[buf][0][p * 1024 + tid * 4], 16, 0, 0);
      __builtin_amdgcn_global_load_lds(
          (const __attribute__((address_space(1))) void*)s2,
          (__attribute__((address_space(3))) void*)&sA[buf][1][p * 1024 + tid * 4], 16, 0, 0);
    }
  };

  stage(0);
  __syncthreads();

  #pragma unroll 1
  for (int gi = 0; gi < ngrp; ++gi){
    if (gi + 1 < ngrp) stage(gi + 1);               // prefetch: in flight under compute

    const int g     = REV ? (ngrp - 1 - gi) : gi;
    const int buf   = gi & 1;
    const int kbase = k0 + g * 64;
    #pragma unroll
    for (int j = 0; j < 2; ++j){
      const int gr0 = j * 8 + qh * 2;
      const int o0  = rl * 64 + ((gr0     ^ sw) << 2);
      const int o1  = rl * 64 + (((gr0+1) ^ sw) << 2);
      f32x4 lo1 = *(const f32x4*)&sA[buf][0][o0];
      f32x4 hi1 = *(const f32x4*)&sA[buf][0][o1];
      f32x4 lo2 = *(const f32x4*)&sA[buf][1][o0];
      f32x4 hi2 = *(const f32x4*)&sA[buf][1][o1];
      short8 b[4];
      const size_t bk = (size_t)kbase + j * 32 + qh * 8;
      #pragma unroll
      for (int f = 0; f < 4; ++f)
        b[f] = *(const short8*)(Bt + (size_t)(f * 16 + (lane & 15)) * NN + bk);
      short8 fa1 = cvt8(lo1, hi1);
      short8 fa2 = cvt8(lo2, hi2);
      #pragma unroll
      for (int f = 0; f < 4; ++f){
        acc1[f] = __builtin_amdgcn_mfma_f32_16x16x32_bf16(fa1, b[f], acc1[f], 0, 0, 0);
        acc2[f] = __builtin_amdgcn_mfma_f32_16x16x32_bf16(fa2, b[f], acc2[f], 0, 0, 0);
      }
    }
    __syncthreads();                                // drains stage(gi+1) + WAR guard
  }

  // D layout: col = lane&15, row = (lane>>4)*4 + reg
  const int orow = bm * 64 + wave * 16 + qh * 4;
  const int col  = lane & 15;
  float* p1 = P1 + ((size_t)ks * NN + orow) * HID_DIM + col;
  float* p2 = P2 + ((size_t)ks * NN + orow) * HID_DIM + col;
  #pragma unroll
  for (int r = 0; r < 4; ++r){
    #pragma unroll
    for (int f = 0; f < 4; ++f){
      p1[(size_t)r * HID_DIM + f * 16] = acc1[f][r];
      p2[(size_t)r * HID_DIM + f * 16] = acc2[f][r];
    }
  }
}

// l1_combine: H1t[c][r] = bf16( relu(SY1+b1) + relu(SY2+b1) ), LDS transpose
// for coalesced bf16 stores. Block = 64 rows.
__global__ __launch_bounds__(256) void l1_combine(const float* __restrict__ Y1p, const float* __restrict__ Y2p,
                                                  const float* __restrict__ b1,
                                                  short* __restrict__ H1t, int S){
  __shared__ float sH[64][65];
  const int tid = threadIdx.x, lane = tid & 63, wave = tid >> 6;
  const int rb = blockIdx.x * 64;
  const float bc = b1[lane];
  #pragma unroll 4
  for (int rq = 0; rq < 16; ++rq){
    const int r = rq * 4 + wave;
    const int row = rb + r;
    float s1 = 0.f, s2 = 0.f;
    for (int sp = 0; sp < S; ++sp){
      s1 += Y1p[((size_t)sp * NN + row) * HID_DIM + lane];
      s2 += Y2p[((size_t)sp * NN + row) * HID_DIM + lane];
    }
    sH[r][lane] = fmaxf(s1 + bc, 0.f) + fmaxf(s2 + bc, 0.f);
  }
  __syncthreads();
  #pragma unroll 4
  for (int i = 0; i < 16; ++i){
    const int c = wave * 16 + i;
    H1t[(size_t)c * NN + rb + lane] = f2bf_bits(sH[lane][c]);
  }
}

// l2_combine: out[row][c] = relu(Z1@W2+b2) + relu(Z2@W2+b2)
__global__ __launch_bounds__(256) void l2_combine(const float* __restrict__ Z1p, const float* __restrict__ Z2p,
                                                  const float* __restrict__ W2, const float* __restrict__ b2,
                                                  float* __restrict__ out, int S){
  __shared__ float sW[HID_DIM * OUT_DIM];
  __shared__ float sb[OUT_DIM];
  __shared__ float sz[4][2][HID_DIM];
  const int tid = threadIdx.x;
  for (int i = tid; i < HID_DIM * OUT_DIM; i += 256) sW[i] = W2[i];
  if (tid < OUT_DIM) sb[tid] = b2[tid];
  const int sub = tid >> 6, t = tid & 63;
  const int row = blockIdx.x * 4 + sub;
  float s1 = 0.f, s2 = 0.f;
  for (int sp = 0; sp < S; ++sp){
    s1 += Z1p[((size_t)sp * NN + row) * HID_DIM + t];
    s2 += Z2p[((size_t)sp * NN + row) * HID_DIM + t];
  }
  sz[sub][0][t] = s1;
  sz[sub][1][t] = s2;
  __syncthreads();
  if (t < OUT_DIM){
    float a = sb[t], b = sb[t];
    #pragma unroll
    for (int k = 0; k < HID_DIM; ++k){
      a += sz[sub][0][k] * sW[k * OUT_DIM + t];
      b += sz[sub][1][k] * sW[k * OUT_DIM + t];
    }
    out[(size_t)row * OUT_DIM + t] = fmaxf(a, 0.f) + fmaxf(b, 0.f);
  }
}

extern "C" void kernel_launch(void* const* d_in, const int* in_sizes, int n_in,
                              void* d_out, int out_size, void* d_ws, size_t ws_size,
                              hipStream_t stream){
  const float* adj1 = (const float*)d_in[0];
  const float* adj2 = (const float*)d_in[1];
  const float* X    = (const float*)d_in[2];
  const float* W1   = (const float*)d_in[3];
  const float* b1   = (const float*)d_in[4];
  const float* W2   = (const float*)d_in[5];
  const float* b2   = (const float*)d_in[6];
  float* out = (float*)d_out;

  char* ws = (char*)d_ws;
  short* Gt  = (short*)ws;                           // 64*8192*2 = 1 MB
  short* H1t = (short*)(ws + (size_t)1024 * 1024);   // 1 MB
  const size_t off = (size_t)2 * 1024 * 1024;

  int S = 4;
  while (S > 1 && off + (size_t)S * 4 * 1024 * 1024 > ws_size) S >>= 1;
  float* P1 = (float*)(ws + off);
  float* P2 = P1 + (size_t)S * NN * HID_DIM;
  const int klen = NN / S;

  k_g        <<<dim3(2048),       dim3(256), 0, stream>>>(X, W1, Gt);
  mm_db<0>   <<<dim3(NN / 64, S), dim3(256), 0, stream>>>(adj1, adj2, Gt, P1, P2, klen);
  l1_combine <<<dim3(NN / 64),    dim3(256), 0, stream>>>(P1, P2, b1, H1t, S);
  mm_db<1>   <<<dim3(NN / 64, S), dim3(256), 0, stream>>>(adj1, adj2, H1t, P1, P2, klen);
  l2_combine <<<dim3(NN / 4),     dim3(256), 0, stream>>>(P1, P2, W2, b2, out, S);
}